// Round 1
// baseline (290.744 us; speedup 1.0000x reference)
//
#include <hip/hip_runtime.h>

#define EMBED 768
#define NH 12
#define HD 64
#define SEQ 4096
#define BATCH 2
#define MROWS (BATCH * SEQ)   // 8192
#define N3E (3 * EMBED)       // 2304

typedef short bf16x8 __attribute__((ext_vector_type(8)));  // 8 bf16 = 4 VGPRs
typedef float fx4 __attribute__((ext_vector_type(4)));     // MFMA C/D
typedef unsigned short ushort_t;
typedef unsigned short us4 __attribute__((ext_vector_type(4)));  // 8B packed

#if __has_builtin(__builtin_amdgcn_exp2f)
#define EXP2F(x) __builtin_amdgcn_exp2f(x)
#else
#define EXP2F(x) exp2f(x)
#endif

// Q pre-scale: (1/sqrt(64)) * log2(e)  -> softmax runs in exp2 domain
#define QSCALE 0.18033688011112042f

// fp32 -> bf16 round-to-nearest-even
__device__ inline ushort_t f2bf(float f) {
  union { float f; unsigned int u; } x; x.f = f;
  unsigned int r = x.u + 0x7fffu + ((x.u >> 16) & 1u);
  return (ushort_t)(r >> 16);
}

// ---------------------------------------------------------------------------
// x [M,K] fp32 -> bf16, straight copy. 8 elems/thread.
// ---------------------------------------------------------------------------
__global__ __launch_bounds__(256) void convert_x(const float* __restrict__ in,
                                                 ushort_t* __restrict__ out) {
  int i = (blockIdx.x * 256 + threadIdx.x) * 8;
  float4 a = *(const float4*)(in + i);
  float4 b = *(const float4*)(in + i + 4);
  bf16x8 o;
  o[0] = f2bf(a.x); o[1] = f2bf(a.y); o[2] = f2bf(a.z); o[3] = f2bf(a.w);
  o[4] = f2bf(b.x); o[5] = f2bf(b.y); o[6] = f2bf(b.z); o[7] = f2bf(b.w);
  *(bf16x8*)(out + i) = o;
}

// ---------------------------------------------------------------------------
// W [K,N] fp32 -> W^T [N,K] bf16 via 64x64 LDS tile (stride 65: conflict-free)
// ---------------------------------------------------------------------------
__global__ __launch_bounds__(256) void transpose_w(const float* __restrict__ in,
                                                   ushort_t* __restrict__ out,
                                                   int K, int N) {
  __shared__ float t[64][65];
  const int bn = blockIdx.x * 64, bk = blockIdx.y * 64;
  const int c = threadIdx.x & 63, r0 = threadIdx.x >> 6;
#pragma unroll
  for (int rr = 0; rr < 16; ++rr) {
    int row = rr * 4 + r0;
    t[row][c] = in[(size_t)(bk + row) * N + bn + c];
  }
  __syncthreads();
#pragma unroll
  for (int rr = 0; rr < 16; ++rr) {
    int row = rr * 4 + r0;
    out[(size_t)(bn + row) * K + bk + c] = f2bf(t[c][row]);
  }
}

// ---------------------------------------------------------------------------
// bf16 MFMA GEMM (m97 structure): C[M,N] = A[M,K] @ Bt[N,K]^T + bias.
// 128x128 tile, BK=32, 4 waves x (64x64), global_load_lds width-16 staging,
// XOR-swizzled [m][k-slot] LDS layout.
// SCATTER: N==2304 -> q (pre-scaled QSCALE, [B,H,S,D]) / k ([B,H,S,D]) /
//          v (transposed [B,H,D,S]) bf16 buffers.  else: fp32 [M,N] out.
// ---------------------------------------------------------------------------
template <int N_, int K_, bool SCATTER>
__global__ __launch_bounds__(256) void gemm_mfma(
    const ushort_t* __restrict__ A, const ushort_t* __restrict__ Bt,
    const float* __restrict__ bias, float* __restrict__ outF,
    ushort_t* __restrict__ oq, ushort_t* __restrict__ ok,
    ushort_t* __restrict__ ov) {
  __shared__ __align__(16) ushort_t As[128 * 32];
  __shared__ __align__(16) ushort_t Bs[128 * 32];
  const int tid = threadIdx.x;
  const int w = tid >> 6, lane = tid & 63;
  const int quad = lane >> 4, ln = lane & 15;
  const int bm = blockIdx.y * 128, bn = blockIdx.x * 128;
  const int wm = (w >> 1) * 64, wn = (w & 1) * 64;

  const int sr = lane >> 2;     // row within 16-row chunk
  const int sslot = lane & 3;   // 16B slot within row

  fx4 acc[4][4] = {};

  for (int k0 = 0; k0 < K_; k0 += 32) {
    __syncthreads();
#pragma unroll
    for (int r = 0; r < 2; ++r) {
      const int c = w + r * 4;        // chunk 0..7 (wave-uniform)
      const int m = c * 16 + sr;      // tile row 0..127
      const int kk = k0 + ((sslot ^ (m & 3)) << 3);
      __builtin_amdgcn_global_load_lds(
          (const __attribute__((address_space(1))) unsigned int*)
              (A + (size_t)(bm + m) * K_ + kk),
          (__attribute__((address_space(3))) unsigned int*)(As + c * 512),
          16, 0, 0);
      __builtin_amdgcn_global_load_lds(
          (const __attribute__((address_space(1))) unsigned int*)
              (Bt + (size_t)(bn + m) * K_ + kk),
          (__attribute__((address_space(3))) unsigned int*)(Bs + c * 512),
          16, 0, 0);
    }
    __syncthreads();

    bf16x8 af[4], bfr[4];
#pragma unroll
    for (int i = 0; i < 4; ++i) {
      const int m = wm + i * 16 + ln;
      af[i] = *(const bf16x8*)(As + m * 32 + ((quad ^ (m & 3)) << 3));
    }
#pragma unroll
    for (int j = 0; j < 4; ++j) {
      const int n = wn + j * 16 + ln;
      bfr[j] = *(const bf16x8*)(Bs + n * 32 + ((quad ^ (n & 3)) << 3));
    }
#pragma unroll
    for (int i = 0; i < 4; ++i)
#pragma unroll
      for (int j = 0; j < 4; ++j)
        acc[i][j] = __builtin_amdgcn_mfma_f32_16x16x32_bf16(af[i], bfr[j],
                                                            acc[i][j], 0, 0, 0);
  }

  if (!SCATTER) {
#pragma unroll
    for (int j = 0; j < 4; ++j) {
      const int n = bn + wn + j * 16 + ln;
      const float bv = bias[n];
#pragma unroll
      for (int i = 0; i < 4; ++i) {
        const int m0 = bm + wm + i * 16 + quad * 4;
#pragma unroll
        for (int r = 0; r < 4; ++r)
          outF[(size_t)(m0 + r) * N_ + n] = acc[i][j][r] + bv;
      }
    }
  } else {
    const int t = bn / EMBED;  // 768 % 128 == 0: whole tile in one of q/k/v
#pragma unroll
    for (int j = 0; j < 4; ++j) {
      const int nn = bn + wn + j * 16 + ln;
      const int rem = nn - t * EMBED;
      const int h = rem >> 6, d = rem & 63;
      const float bv = bias[nn];
#pragma unroll
      for (int i = 0; i < 4; ++i) {
        const int m0 = bm + wm + i * 16 + quad * 4;
#pragma unroll
        for (int r = 0; r < 4; ++r) {
          const int m = m0 + r;
          const int b_ = m >> 12, s = m & 4095;
          const float v = acc[i][j][r] + bv;
          if (t == 0)
            oq[((size_t)(b_ * NH + h) * SEQ + s) * HD + d] = f2bf(v * QSCALE);
          else if (t == 1)
            ok[((size_t)(b_ * NH + h) * SEQ + s) * HD + d] = f2bf(v);
          else
            ov[((size_t)(b_ * NH + h) * HD + d) * SEQ + s] = f2bf(v);
        }
      }
    }
  }
}

// ---------------------------------------------------------------------------
// Causal flash attention, bf16 MFMA, fp32 accumulate.  QBLK = 128 (v2):
//  * Each block owns TWO 64-row q-groups (A = rows qt2*128..+63, B = +64..+127)
//    sharing every K-fragment and V-fragment LDS read -> DS cycles per MFMA
//    drop from ~15 to ~9 (theory: flash was LDS-throughput-bound ~3x over its
//    MFMA floor; all 4 waves read identical K/V frags, each fed only 1-2 MFMAs).
//  * LDS = 49152 B (Ks/Vt dbuf 16K+16K, Ps 128x64 = 16K) -> 3 blocks/CU,
//    12 waves/CU.  Grid (24,32) = 768 blocks = exactly co-resident.
//  * Stratified y->qt2 map (y<11 -> 31-y else y-11): stride-256 CU triples
//    draw one block from each work stratum -> makespan tail ~+10% (vs +35%
//    for plain descending with no backfill queue).
//  * Group A k-range: kt <= 2*qt2 (diag at 2*qt2); group B: kt <= 2*qt2+1
//    (diag at last).  Only the final iteration runs B solo.
//  * FIXED-SHIFT softmax (p = exp2(s) raw), S^T trick (lane owns q-row ln),
//    PV operand-swap (O^T, l lane-local), same XOR-swizzled Ps granules.
//  * s_setprio(1) around PV MFMA clusters (T5).
// ---------------------------------------------------------------------------
__global__ __launch_bounds__(256, 3) void flash_mfma(
    const ushort_t* __restrict__ qb, const ushort_t* __restrict__ kb,
    const ushort_t* __restrict__ vb, ushort_t* __restrict__ attn) {
  __shared__ __align__(16) ushort_t Ks[2][64 * 64];   // 16384 B
  __shared__ __align__(16) ushort_t Vt[2][64 * 64];   // 16384 B
  __shared__ __align__(16) ushort_t Ps[128 * 64];     // 16384 B, swizzled

  const int tid = threadIdx.x;
  const int w = tid >> 6;
  const int lane = tid & 63;
  const int quad = lane >> 4;
  const int ln = lane & 15;

  const int bh = blockIdx.x;  // 0..23 (fast dim, 24%8==0 -> XCD = bh%8)
  const int y = blockIdx.y;   // 0..31
  // stratified work map: qt2 strata {21..31},{0..10},{11..20} along y
  const int qt2 = (y < 11) ? (31 - y) : (y - 11);
  const int ktd0 = 2 * qt2;      // group A diagonal k-tile
  const int nkt = 2 * qt2 + 2;   // k-tiles; group B diagonal at nkt-1

  const size_t base = (size_t)bh * SEQ * HD;
  const ushort_t* Qg = qb + base;
  const ushort_t* Kg = kb + base;
  const ushort_t* Vg = vb + base;  // [HD][SEQ]

  // ---- staging geometry (kt-invariant) ----
  const int srow = lane >> 3;
  const int sg = (lane & 7) ^ srow;     // logical granule this lane fetches
  const int row0 = w * 8 + srow;        // chunk w row (chunk w+4 = +32)
  const ushort_t* kp = Kg + (size_t)row0 * HD + (sg << 3);
  const ushort_t* vp = Vg + (size_t)row0 * SEQ + (sg << 3);

  // ---- fragment offsets (elements, kt-invariant) ----
  const int m7 = ln & 7;
  int koff[4], voff[2][4], pwoff[4], proff[2];
#pragma unroll
  for (int t = 0; t < 4; ++t) {
    koff[t] = (t * 16 + ln) * 64 + ((quad ^ m7) << 3);
    voff[0][t] = (t * 16 + ln) * 64 + ((quad ^ m7) << 3);
    voff[1][t] = (t * 16 + ln) * 64 + (((4 + quad) ^ m7) << 3);
    pwoff[t] = (w * 16 + ln) * 64 + (((t * 2 + (quad >> 1)) ^ m7) << 3) +
               (quad & 1) * 4;
  }
  proff[0] = (w * 16 + ln) * 64 + ((quad ^ m7) << 3);
  proff[1] = (w * 16 + ln) * 64 + (((4 + quad) ^ m7) << 3);

  const int b_ = bh / NH, h = bh % NH;
  const int prow = w * 16 + ln;           // lane's q-row within a 64-group
  const int rowA = qt2 * 128 + prow;      // group A global q-row (B = +64)

  // ---- Q fragments, both groups (kt-invariant) ----
  bf16x8 qfA0, qfA1, qfB0, qfB1;
  {
    const ushort_t* qa = Qg + (size_t)rowA * HD;
    qfA0 = *(const bf16x8*)(qa + quad * 8);
    qfA1 = *(const bf16x8*)(qa + 32 + quad * 8);
    const ushort_t* qbr = Qg + (size_t)(rowA + 64) * HD;
    qfB0 = *(const bf16x8*)(qbr + quad * 8);
    qfB1 = *(const bf16x8*)(qbr + 32 + quad * 8);
  }
  fx4 oaccA[4] = {}, oaccB[4] = {};  // O^T: col = qr = ln (lane-local), row = d
  float lA = 0.f, lB = 0.f;          // per-lane partial sums of p

  // ---- prologue: stage kt=0 into buf 0; advance pointers to kt=1 ----
#pragma unroll
  for (int r2 = 0; r2 < 2; ++r2) {
    __builtin_amdgcn_global_load_lds(
        (const __attribute__((address_space(1))) unsigned int*)(kp + r2 * (32 * HD)),
        (__attribute__((address_space(3))) unsigned int*)(&Ks[0][(w + r2 * 4) * 512]),
        16, 0, 0);
    __builtin_amdgcn_global_load_lds(
        (const __attribute__((address_space(1))) unsigned int*)(vp + r2 * (32 * SEQ)),
        (__attribute__((address_space(3))) unsigned int*)(&Vt[0][(w + r2 * 4) * 512]),
        16, 0, 0);
  }
  kp += 64 * HD;
  vp += 64;

  for (int kt = 0; kt < nkt; ++kt) {
    const int cur = kt & 1;
    __syncthreads();  // publish buf `cur` (drains in-flight DMA)
    if (kt + 1 < nkt) {  // prefetch kt+1 into the other buffer
      const int nxt = cur ^ 1;
#pragma unroll
      for (int r2 = 0; r2 < 2; ++r2) {
        __builtin_amdgcn_global_load_lds(
            (const __attribute__((address_space(1))) unsigned int*)(kp + r2 * (32 * HD)),
            (__attribute__((address_space(3))) unsigned int*)(&Ks[nxt][(w + r2 * 4) * 512]),
            16, 0, 0);
        __builtin_amdgcn_global_load_lds(
            (const __attribute__((address_space(1))) unsigned int*)(vp + r2 * (32 * SEQ)),
            (__attribute__((address_space(3))) unsigned int*)(&Vt[nxt][(w + r2 * 4) * 512]),
            16, 0, 0);
      }
      kp += 64 * HD;
      vp += 64;
    }

    const bool dual = (kt <= ktd0);        // group A still active
    const bool diagA = (kt == ktd0);
    const bool diagB = (kt == nkt - 1);

    // S^T tile t for both groups: shared kf reads -> MFMA -> exp2 -> pack -> Ps
    auto do_t = [&](int t) {
      bf16x8 kf0 = *(const bf16x8*)(&Ks[cur][koff[t]]);
      bf16x8 kf1 = *(const bf16x8*)(&Ks[cur][koff[t] ^ 32]);
      // ---- group B (always active) ----
      {
        uint2 pr;
        if (diagB && t > w) {
          pr.x = 0u; pr.y = 0u;  // fully masked 16-kr chunk: p = 0
        } else {
          fx4 c = {};
          c = __builtin_amdgcn_mfma_f32_16x16x32_bf16(kf0, qfB0, c, 0, 0, 0);
          c = __builtin_amdgcn_mfma_f32_16x16x32_bf16(kf1, qfB1, c, 0, 0, 0);
          if (diagB && t == w) {
#pragma unroll
            for (int r = 0; r < 4; ++r)
              if (quad * 4 + r > ln) c[r] = -1e30f;  // exp2 -> 0
          }
          unsigned int u[4];
#pragma unroll
          for (int r = 0; r < 4; ++r) {
            float e = EXP2F(c[r]);
            lB += e;
            union { float f; unsigned int u; } x; x.f = e;
            u[r] = x.u + 0x8000u;  // half-up round to bf16
          }
          pr.x = __builtin_amdgcn_perm(u[1], u[0], 0x07060302u);
          pr.y = __builtin_amdgcn_perm(u[3], u[2], 0x07060302u);
        }
        *(uint2*)&Ps[4096 + pwoff[t]] = pr;
      }
      // ---- group A (shares kf0/kf1) ----
      if (dual) {
        uint2 pr;
        if (diagA && t > w) {
          pr.x = 0u; pr.y = 0u;
        } else {
          fx4 c = {};
          c = __builtin_amdgcn_mfma_f32_16x16x32_bf16(kf0, qfA0, c, 0, 0, 0);
          c = __builtin_amdgcn_mfma_f32_16x16x32_bf16(kf1, qfA1, c, 0, 0, 0);
          if (diagA && t == w) {
#pragma unroll
            for (int r = 0; r < 4; ++r)
              if (quad * 4 + r > ln) c[r] = -1e30f;
          }
          unsigned int u[4];
#pragma unroll
          for (int r = 0; r < 4; ++r) {
            float e = EXP2F(c[r]);
            lA += e;
            union { float f; unsigned int u; } x; x.f = e;
            u[r] = x.u + 0x8000u;
          }
          pr.x = __builtin_amdgcn_perm(u[1], u[0], 0x07060302u);
          pr.y = __builtin_amdgcn_perm(u[3], u[2], 0x07060302u);
        }
        *(uint2*)&Ps[pwoff[t]] = pr;
      }
    };

    do_t(0);
    do_t(1);
    // P first half ready (own wave's rows; DS in-order per wave).
    bf16x8 pf0B = *(const bf16x8*)&Ps[4096 + proff[0]];
    bf16x8 pf0A = {};
    if (dual) pf0A = *(const bf16x8*)&Ps[proff[0]];
    do_t(2);
    do_t(3);
    // ---- O^T += V^T.P, kr 0..31 (each vf feeds both groups) ----
    __builtin_amdgcn_s_setprio(1);
#pragma unroll
    for (int t = 0; t < 4; ++t) {
      bf16x8 vf = *(const bf16x8*)(&Vt[cur][voff[0][t]]);
      oaccB[t] = __builtin_amdgcn_mfma_f32_16x16x32_bf16(vf, pf0B, oaccB[t], 0, 0, 0);
      if (dual)
        oaccA[t] = __builtin_amdgcn_mfma_f32_16x16x32_bf16(vf, pf0A, oaccA[t], 0, 0, 0);
    }
    __builtin_amdgcn_s_setprio(0);
    // ---- O^T += V^T.P, kr 32..63 ----
    bf16x8 pf1B = *(const bf16x8*)&Ps[4096 + proff[1]];
    bf16x8 pf1A = {};
    if (dual) pf1A = *(const bf16x8*)&Ps[proff[1]];
    __builtin_amdgcn_s_setprio(1);
#pragma unroll
    for (int t = 0; t < 4; ++t) {
      bf16x8 vf = *(const bf16x8*)(&Vt[cur][voff[1][t]]);
      oaccB[t] = __builtin_amdgcn_mfma_f32_16x16x32_bf16(vf, pf1B, oaccB[t], 0, 0, 0);
      if (dual)
        oaccA[t] = __builtin_amdgcn_mfma_f32_16x16x32_bf16(vf, pf1A, oaccA[t], 0, 0, 0);
    }
    __builtin_amdgcn_s_setprio(0);
  }

  // ---- l reductions + epilogue: O^T/l -> attn bf16 [B,S,E], both groups ----
  lA += __shfl_xor(lA, 16);
  lA += __shfl_xor(lA, 32);
  lB += __shfl_xor(lB, 16);
  lB += __shfl_xor(lB, 32);
  const float invA = 1.f / lA;
  const float invB = 1.f / lB;
  ushort_t* orowA = attn + (size_t)(b_ * SEQ + rowA) * EMBED + h * HD;
  ushort_t* orowB = attn + (size_t)(b_ * SEQ + rowA + 64) * EMBED + h * HD;
#pragma unroll
  for (int t = 0; t < 4; ++t) {
    us4 oA, oB;
#pragma unroll
    for (int r = 0; r < 4; ++r) {
      oA[r] = f2bf(oaccA[t][r] * invA);
      oB[r] = f2bf(oaccB[t][r] * invB);
    }
    *(us4*)(orowA + t * 16 + quad * 4) = oA;
    *(us4*)(orowB + t * 16 + quad * 4) = oB;
  }
}

extern "C" void kernel_launch(void* const* d_in, const int* in_sizes, int n_in,
                              void* d_out, int out_size, void* d_ws,
                              size_t ws_size, hipStream_t stream) {
  const float* x = (const float*)d_in[0];      // [B,S,E]
  const float* w_qkv = (const float*)d_in[1];  // [E,3E]
  const float* b_qkv = (const float*)d_in[2];  // [3E]
  const float* w_out = (const float*)d_in[3];  // [E,E]
  const float* b_out = (const float*)d_in[4];  // [E]
  float* out = (float*)d_out;                  // [B,S,E] fp32

  const size_t per = (size_t)BATCH * NH * SEQ * HD;  // 6291456
  ushort_t* q_buf = (ushort_t*)d_ws;          // [B,H,S,D] (scaled by QSCALE)
  ushort_t* k_buf = q_buf + per;              // [B,H,S,D]
  ushort_t* v_buf = k_buf + per;              // [B,H,D,S] (transposed)
  ushort_t* attn_buf = v_buf + per;           // [B,S,E] bf16
  ushort_t* xb = attn_buf + per;              // [M,E] bf16
  ushort_t* wqkvT = xb + per;                 // [3E,E] bf16
  ushort_t* woutT = wqkvT + (size_t)N3E * EMBED;  // [E,E] bf16

  convert_x<<<(MROWS * EMBED) / 2048, 256, 0, stream>>>(x, xb);
  transpose_w<<<dim3(N3E / 64, EMBED / 64), 256, 0, stream>>>(w_qkv, wqkvT,
                                                              EMBED, N3E);
  transpose_w<<<dim3(EMBED / 64, EMBED / 64), 256, 0, stream>>>(w_out, woutT,
                                                                EMBED, EMBED);

  dim3 g1(N3E / 128, MROWS / 128);  // (18,64)
  gemm_mfma<N3E, EMBED, true><<<g1, 256, 0, stream>>>(
      xb, wqkvT, b_qkv, nullptr, q_buf, k_buf, v_buf);

  dim3 g2(BATCH * NH, 32);  // bh fast (XCD = bh%8); stratified qt2 map in-kernel
  flash_mfma<<<g2, 256, 0, stream>>>(q_buf, k_buf, v_buf, attn_buf);

  dim3 g3(EMBED / 128, MROWS / 128);  // (6,64)
  gemm_mfma<EMBED, EMBED, false><<<g3, 256, 0, stream>>>(
      attn_buf, woutT, b_out, out, nullptr, nullptr, nullptr);
}

// Round 2
// 260.586 us; speedup vs baseline: 1.1157x; 1.1157x over previous
//
#include <hip/hip_runtime.h>

#define EMBED 768
#define NH 12
#define HD 64
#define SEQ 4096
#define BATCH 2
#define MROWS (BATCH * SEQ)   // 8192
#define N3E (3 * EMBED)       // 2304

typedef short bf16x8 __attribute__((ext_vector_type(8)));  // 8 bf16 = 4 VGPRs
typedef float fx4 __attribute__((ext_vector_type(4)));     // MFMA C/D 16x16
typedef float f32x16 __attribute__((ext_vector_type(16))); // MFMA C/D 32x32
typedef unsigned short ushort_t;
typedef unsigned short us4 __attribute__((ext_vector_type(4)));  // 8B packed

#if __has_builtin(__builtin_amdgcn_exp2f)
#define EXP2F(x) __builtin_amdgcn_exp2f(x)
#else
#define EXP2F(x) exp2f(x)
#endif

// Q pre-scale: (1/sqrt(64)) * log2(e)  -> softmax runs in exp2 domain
#define QSCALE 0.18033688011112042f

// fp32 -> bf16 round-to-nearest-even
__device__ inline ushort_t f2bf(float f) {
  union { float f; unsigned int u; } x; x.f = f;
  unsigned int r = x.u + 0x7fffu + ((x.u >> 16) & 1u);
  return (ushort_t)(r >> 16);
}

// v_cvt_pk_bf16_f32: D = {lo: bf16(a), hi: bf16(b)} (no builtin on gfx950)
__device__ inline unsigned int cvtpk(float a, float b) {
  unsigned int r;
  asm("v_cvt_pk_bf16_f32 %0, %1, %2" : "=v"(r) : "v"(a), "v"(b));
  return r;
}

// v_permlane32_swap_b32: x[hi lanes] <-> y[lo lanes]
__device__ inline void plswap(unsigned int& x, unsigned int& y) {
  asm("v_permlane32_swap_b32 %0, %1" : "+v"(x), "+v"(y));
}

// ---------------------------------------------------------------------------
// x [M,K] fp32 -> bf16, straight copy. 8 elems/thread.
// ---------------------------------------------------------------------------
__global__ __launch_bounds__(256) void convert_x(const float* __restrict__ in,
                                                 ushort_t* __restrict__ out) {
  int i = (blockIdx.x * 256 + threadIdx.x) * 8;
  float4 a = *(const float4*)(in + i);
  float4 b = *(const float4*)(in + i + 4);
  bf16x8 o;
  o[0] = f2bf(a.x); o[1] = f2bf(a.y); o[2] = f2bf(a.z); o[3] = f2bf(a.w);
  o[4] = f2bf(b.x); o[5] = f2bf(b.y); o[6] = f2bf(b.z); o[7] = f2bf(b.w);
  *(bf16x8*)(out + i) = o;
}

// ---------------------------------------------------------------------------
// W [K,N] fp32 -> W^T [N,K] bf16 via 64x64 LDS tile (stride 65: conflict-free)
// ---------------------------------------------------------------------------
__global__ __launch_bounds__(256) void transpose_w(const float* __restrict__ in,
                                                   ushort_t* __restrict__ out,
                                                   int K, int N) {
  __shared__ float t[64][65];
  const int bn = blockIdx.x * 64, bk = blockIdx.y * 64;
  const int c = threadIdx.x & 63, r0 = threadIdx.x >> 6;
#pragma unroll
  for (int rr = 0; rr < 16; ++rr) {
    int row = rr * 4 + r0;
    t[row][c] = in[(size_t)(bk + row) * N + bn + c];
  }
  __syncthreads();
#pragma unroll
  for (int rr = 0; rr < 16; ++rr) {
    int row = rr * 4 + r0;
    out[(size_t)(bn + row) * K + bk + c] = f2bf(t[c][row]);
  }
}

// ---------------------------------------------------------------------------
// bf16 MFMA GEMM (m97 structure): C[M,N] = A[M,K] @ Bt[N,K]^T + bias.
// 128x128 tile, BK=32, 4 waves x (64x64), global_load_lds width-16 staging,
// XOR-swizzled [m][k-slot] LDS layout.
// SCATTER: N==2304 -> q (pre-scaled QSCALE, [B,H,S,D]) / k ([B,H,S,D]) /
//          v (transposed [B,H,D,S]) bf16 buffers.  else: fp32 [M,N] out.
// ---------------------------------------------------------------------------
template <int N_, int K_, bool SCATTER>
__global__ __launch_bounds__(256) void gemm_mfma(
    const ushort_t* __restrict__ A, const ushort_t* __restrict__ Bt,
    const float* __restrict__ bias, float* __restrict__ outF,
    ushort_t* __restrict__ oq, ushort_t* __restrict__ ok,
    ushort_t* __restrict__ ov) {
  __shared__ __align__(16) ushort_t As[128 * 32];
  __shared__ __align__(16) ushort_t Bs[128 * 32];
  const int tid = threadIdx.x;
  const int w = tid >> 6, lane = tid & 63;
  const int quad = lane >> 4, ln = lane & 15;
  const int bm = blockIdx.y * 128, bn = blockIdx.x * 128;
  const int wm = (w >> 1) * 64, wn = (w & 1) * 64;

  const int sr = lane >> 2;     // row within 16-row chunk
  const int sslot = lane & 3;   // 16B slot within row

  fx4 acc[4][4] = {};

  for (int k0 = 0; k0 < K_; k0 += 32) {
    __syncthreads();
#pragma unroll
    for (int r = 0; r < 2; ++r) {
      const int c = w + r * 4;        // chunk 0..7 (wave-uniform)
      const int m = c * 16 + sr;      // tile row 0..127
      const int kk = k0 + ((sslot ^ (m & 3)) << 3);
      __builtin_amdgcn_global_load_lds(
          (const __attribute__((address_space(1))) unsigned int*)
              (A + (size_t)(bm + m) * K_ + kk),
          (__attribute__((address_space(3))) unsigned int*)(As + c * 512),
          16, 0, 0);
      __builtin_amdgcn_global_load_lds(
          (const __attribute__((address_space(1))) unsigned int*)
              (Bt + (size_t)(bn + m) * K_ + kk),
          (__attribute__((address_space(3))) unsigned int*)(Bs + c * 512),
          16, 0, 0);
    }
    __syncthreads();

    bf16x8 af[4], bfr[4];
#pragma unroll
    for (int i = 0; i < 4; ++i) {
      const int m = wm + i * 16 + ln;
      af[i] = *(const bf16x8*)(As + m * 32 + ((quad ^ (m & 3)) << 3));
    }
#pragma unroll
    for (int j = 0; j < 4; ++j) {
      const int n = wn + j * 16 + ln;
      bfr[j] = *(const bf16x8*)(Bs + n * 32 + ((quad ^ (n & 3)) << 3));
    }
#pragma unroll
    for (int i = 0; i < 4; ++i)
#pragma unroll
      for (int j = 0; j < 4; ++j)
        acc[i][j] = __builtin_amdgcn_mfma_f32_16x16x32_bf16(af[i], bfr[j],
                                                            acc[i][j], 0, 0, 0);
  }

  if (!SCATTER) {
#pragma unroll
    for (int j = 0; j < 4; ++j) {
      const int n = bn + wn + j * 16 + ln;
      const float bv = bias[n];
#pragma unroll
      for (int i = 0; i < 4; ++i) {
        const int m0 = bm + wm + i * 16 + quad * 4;
#pragma unroll
        for (int r = 0; r < 4; ++r)
          outF[(size_t)(m0 + r) * N_ + n] = acc[i][j][r] + bv;
      }
    }
  } else {
    const int t = bn / EMBED;  // 768 % 128 == 0: whole tile in one of q/k/v
#pragma unroll
    for (int j = 0; j < 4; ++j) {
      const int nn = bn + wn + j * 16 + ln;
      const int rem = nn - t * EMBED;
      const int h = rem >> 6, d = rem & 63;
      const float bv = bias[nn];
#pragma unroll
      for (int i = 0; i < 4; ++i) {
        const int m0 = bm + wm + i * 16 + quad * 4;
#pragma unroll
        for (int r = 0; r < 4; ++r) {
          const int m = m0 + r;
          const int b_ = m >> 12, s = m & 4095;
          const float v = acc[i][j][r] + bv;
          if (t == 0)
            oq[((size_t)(b_ * NH + h) * SEQ + s) * HD + d] = f2bf(v * QSCALE);
          else if (t == 1)
            ok[((size_t)(b_ * NH + h) * SEQ + s) * HD + d] = f2bf(v);
          else
            ov[((size_t)(b_ * NH + h) * HD + d) * SEQ + s] = f2bf(v);
        }
      }
    }
  }
}

// ---------------------------------------------------------------------------
// Causal flash attention v3: 32x32x16 MFMA, fully in-register P.
//  * Swapped QK^T: S^T = K.Q^T via mfma(kf, qf); C layout col=lane&31 (= q,
//    lane-local!), row=(reg&3)+8*(reg>>2)+4*(lane>>5).
//  * P fragments built IN REGISTERS: v_cvt_pk_bf16_f32 pairs + TWO
//    v_permlane32_swap_b32 per 16-kr chunk (T12/m214).  The Ps LDS
//    round-trip (8 writes + 4 reads + in-order DS dependency) is GONE:
//    DS/wave-iter 288 -> 192 CU-cyc, and the softmax->PV latency chain is
//    pure VALU.
//  * LDS = 32768 (Ks/Vt dbuf only) -> capacity 5 blocks/CU; VGPR capped 128
//    via __launch_bounds__(256,4).
//  * Per wave: 32 q-rows (QBLK=128/4 waves), 16 MFMA_32x32 per kt:
//    QK 2 krblk x 4 dchunk, PV 4 chunk x 2 vblk.  K/V frag reads 16 b128,
//    evenly banked via granule swizzle slot = g ^ (row&7).
//  * FIXED-SHIFT softmax (exp2 raw, no max), l lane-local, final
//    __shfl_xor(32); grid (24,32) stratified qt2 map, XCD = bh%8.
// ---------------------------------------------------------------------------
__global__ __launch_bounds__(256, 4) void flash_mfma(
    const ushort_t* __restrict__ qb, const ushort_t* __restrict__ kb,
    const ushort_t* __restrict__ vb, ushort_t* __restrict__ attn) {
  __shared__ __align__(16) ushort_t Ks[2][64 * 64];  // 16384 B
  __shared__ __align__(16) ushort_t Vt[2][64 * 64];  // 16384 B

  const int tid = threadIdx.x;
  const int w = tid >> 6;      // wave -> q sub-block (32 rows)
  const int lane = tid & 63;
  const int r32 = lane & 31;   // MFMA row index
  const int hf = lane >> 5;    // k-half (lane 0-31 vs 32-63)
  const int gk = r32 & 7;      // granule swizzle key
  const int rc4 = hf * 4;      // rowcode offset

  const int bh = blockIdx.x;   // 0..23 (fast dim, 24%8==0 -> XCD = bh%8)
  const int y = blockIdx.y;    // 0..31
  const int qt2 = (y < 11) ? (31 - y) : (y - 11);  // stratified map
  const int ktd0 = 2 * qt2;    // first diagonal k-tile
  const int nkt = 2 * qt2 + 2;

  const size_t base = (size_t)bh * SEQ * HD;
  const ushort_t* Qg = qb + base;
  const ushort_t* Kg = kb + base;
  const ushort_t* Vg = vb + base;  // [HD][SEQ]

  // ---- staging geometry (kt-invariant, same as v2) ----
  const int srow = lane >> 3;
  const int sg = (lane & 7) ^ srow;     // logical granule this lane fetches
  const int row0 = w * 8 + srow;        // chunk w row (chunk w+4 = +32)
  const ushort_t* kp = Kg + (size_t)row0 * HD + (sg << 3);
  const ushort_t* vp = Vg + (size_t)row0 * SEQ + (sg << 3);

  // ---- Q fragments (kt-invariant): B-operand, lane holds Q[q32][dchunk] ----
  const int qoff = w * 32 + r32;        // q offset within 128-row tile
  const int qglob = qt2 * 128 + qoff;
  bf16x8 qf[4];
  {
    const ushort_t* qrow = Qg + (size_t)qglob * HD;
#pragma unroll
    for (int dc = 0; dc < 4; ++dc)
      qf[dc] = *(const bf16x8*)(qrow + dc * 16 + hf * 8);
  }

  f32x16 oacc[2] = {};  // O^T: col q = r32 (lane-local), rows d per vblk
  float lsum = 0.f;

  // ---- prologue: stage kt=0 into buf 0; advance pointers to kt=1 ----
#pragma unroll
  for (int r2 = 0; r2 < 2; ++r2) {
    __builtin_amdgcn_global_load_lds(
        (const __attribute__((address_space(1))) unsigned int*)(kp + r2 * (32 * HD)),
        (__attribute__((address_space(3))) unsigned int*)(&Ks[0][(w + r2 * 4) * 512]),
        16, 0, 0);
    __builtin_amdgcn_global_load_lds(
        (const __attribute__((address_space(1))) unsigned int*)(vp + r2 * (32 * SEQ)),
        (__attribute__((address_space(3))) unsigned int*)(&Vt[0][(w + r2 * 4) * 512]),
        16, 0, 0);
  }
  kp += 64 * HD;
  vp += 64;

  for (int kt = 0; kt < nkt; ++kt) {
    const int cur = kt & 1;
    __syncthreads();  // publish buf `cur` (drains in-flight DMA)
    if (kt + 1 < nkt) {  // prefetch kt+1 into the other buffer
      const int nxt = cur ^ 1;
#pragma unroll
      for (int r2 = 0; r2 < 2; ++r2) {
        __builtin_amdgcn_global_load_lds(
            (const __attribute__((address_space(1))) unsigned int*)(kp + r2 * (32 * HD)),
            (__attribute__((address_space(3))) unsigned int*)(&Ks[nxt][(w + r2 * 4) * 512]),
            16, 0, 0);
        __builtin_amdgcn_global_load_lds(
            (const __attribute__((address_space(1))) unsigned int*)(vp + r2 * (32 * SEQ)),
            (__attribute__((address_space(3))) unsigned int*)(&Vt[nxt][(w + r2 * 4) * 512]),
            16, 0, 0);
      }
      kp += 64 * HD;
      vp += 64;
    }

    const bool diag = (kt >= ktd0);
    const int kbase0 = (kt == ktd0) ? 0 : 64;  // used only when diag

#pragma unroll
    for (int krb = 0; krb < 2; ++krb) {
      // ---- QK^T: S^T[kr 32][q 32], chained over 4 d-chunks ----
      const int krow = (krb * 32 + r32) * 64;
      f32x16 s = {};
#pragma unroll
      for (int dc = 0; dc < 4; ++dc) {
        bf16x8 kf =
            *(const bf16x8*)(&Ks[cur][krow + (((2 * dc + hf) ^ gk) << 3)]);
        s = __builtin_amdgcn_mfma_f32_32x32x16_bf16(kf, qf[dc], s, 0, 0, 0);
      }
      // ---- causal mask (only the last two k-tiles) ----
      if (diag) {
        const int kb2 = kbase0 + krb * 32;
#pragma unroll
        for (int r = 0; r < 16; ++r) {
          const int rowc = (r & 3) + 8 * (r >> 2) + rc4;
          if (kb2 + rowc > qoff) s[r] = -1e30f;
        }
      }
      // ---- exp2 + l ----
      float e[16];
#pragma unroll
      for (int r = 0; r < 16; ++r) {
        e[r] = EXP2F(s[r]);
        lsum += e[r];
      }
      // ---- per 16-kr chunk: pack to bf16, permlane-swap -> pf; PV ----
#pragma unroll
      for (int ch = 0; ch < 2; ++ch) {
        const int rb = ch * 8;
        unsigned int x0 = cvtpk(e[rb + 0], e[rb + 1]);
        unsigned int x1 = cvtpk(e[rb + 2], e[rb + 3]);
        unsigned int y0 = cvtpk(e[rb + 4], e[rb + 5]);
        unsigned int y1 = cvtpk(e[rb + 6], e[rb + 7]);
        plswap(x0, y0);  // x0 -> (j0,j1), y0 -> (j4,j5)
        plswap(x1, y1);  // x1 -> (j2,j3), y1 -> (j6,j7)
        union { unsigned int u[4]; bf16x8 v; } pf;
        pf.u[0] = x0; pf.u[1] = x1; pf.u[2] = y0; pf.u[3] = y1;
        const int c = 2 * krb + ch;       // 16-kr chunk index 0..3
        __builtin_amdgcn_s_setprio(1);
#pragma unroll
        for (int vb2 = 0; vb2 < 2; ++vb2) {
          const int vrow = (vb2 * 32 + r32) * 64;
          bf16x8 vf =
              *(const bf16x8*)(&Vt[cur][vrow + (((2 * c + hf) ^ gk) << 3)]);
          oacc[vb2] =
              __builtin_amdgcn_mfma_f32_32x32x16_bf16(vf, pf.v, oacc[vb2], 0, 0, 0);
        }
        __builtin_amdgcn_s_setprio(0);
      }
    }
  }

  // ---- l reduction (hf pair) + epilogue: O^T/l -> attn bf16 [B,S,E] ----
  lsum += __shfl_xor(lsum, 32);
  const float inv = 1.f / lsum;
  const int b_ = bh / NH, h = bh % NH;
  ushort_t* orow = attn + (size_t)(b_ * SEQ + qglob) * EMBED + h * HD;
#pragma unroll
  for (int vb2 = 0; vb2 < 2; ++vb2)
#pragma unroll
    for (int rq = 0; rq < 4; ++rq) {
      us4 o;
#pragma unroll
      for (int r = 0; r < 4; ++r) o[r] = f2bf(oacc[vb2][rq * 4 + r] * inv);
      *(us4*)(orow + vb2 * 32 + rq * 8 + rc4) = o;
    }
}

extern "C" void kernel_launch(void* const* d_in, const int* in_sizes, int n_in,
                              void* d_out, int out_size, void* d_ws,
                              size_t ws_size, hipStream_t stream) {
  const float* x = (const float*)d_in[0];      // [B,S,E]
  const float* w_qkv = (const float*)d_in[1];  // [E,3E]
  const float* b_qkv = (const float*)d_in[2];  // [3E]
  const float* w_out = (const float*)d_in[3];  // [E,E]
  const float* b_out = (const float*)d_in[4];  // [E]
  float* out = (float*)d_out;                  // [B,S,E] fp32

  const size_t per = (size_t)BATCH * NH * SEQ * HD;  // 6291456
  ushort_t* q_buf = (ushort_t*)d_ws;          // [B,H,S,D] (scaled by QSCALE)
  ushort_t* k_buf = q_buf + per;              // [B,H,S,D]
  ushort_t* v_buf = k_buf + per;              // [B,H,D,S] (transposed)
  ushort_t* attn_buf = v_buf + per;           // [B,S,E] bf16
  ushort_t* xb = attn_buf + per;              // [M,E] bf16
  ushort_t* wqkvT = xb + per;                 // [3E,E] bf16
  ushort_t* woutT = wqkvT + (size_t)N3E * EMBED;  // [E,E] bf16

  convert_x<<<(MROWS * EMBED) / 2048, 256, 0, stream>>>(x, xb);
  transpose_w<<<dim3(N3E / 64, EMBED / 64), 256, 0, stream>>>(w_qkv, wqkvT,
                                                              EMBED, N3E);
  transpose_w<<<dim3(EMBED / 64, EMBED / 64), 256, 0, stream>>>(w_out, woutT,
                                                                EMBED, EMBED);

  dim3 g1(N3E / 128, MROWS / 128);  // (18,64)
  gemm_mfma<N3E, EMBED, true><<<g1, 256, 0, stream>>>(
      xb, wqkvT, b_qkv, nullptr, q_buf, k_buf, v_buf);

  dim3 g2(BATCH * NH, 32);  // bh fast (XCD = bh%8); stratified qt2 map
  flash_mfma<<<g2, 256, 0, stream>>>(q_buf, k_buf, v_buf, attn_buf);

  dim3 g3(EMBED / 128, MROWS / 128);  // (6,64)
  gemm_mfma<EMBED, EMBED, false><<<g3, 256, 0, stream>>>(
      attn_buf, woutT, b_out, out, nullptr, nullptr, nullptr);
}

// Round 3
// 257.699 us; speedup vs baseline: 1.1282x; 1.0112x over previous
//
#include <hip/hip_runtime.h>

#define EMBED 768
#define NH 12
#define HD 64
#define SEQ 4096
#define BATCH 2
#define MROWS (BATCH * SEQ)   // 8192
#define N3E (3 * EMBED)       // 2304

typedef short bf16x8 __attribute__((ext_vector_type(8)));  // 8 bf16 = 4 VGPRs
typedef float fx4 __attribute__((ext_vector_type(4)));     // MFMA C/D 16x16
typedef float f32x16 __attribute__((ext_vector_type(16))); // MFMA C/D 32x32
typedef unsigned short ushort_t;
typedef unsigned short us4 __attribute__((ext_vector_type(4)));  // 8B packed

#if __has_builtin(__builtin_amdgcn_exp2f)
#define EXP2F(x) __builtin_amdgcn_exp2f(x)
#else
#define EXP2F(x) exp2f(x)
#endif

// Q pre-scale: (1/sqrt(64)) * log2(e)  -> softmax runs in exp2 domain
#define QSCALE 0.18033688011112042f

// fp32 -> bf16 round-to-nearest-even
__device__ inline ushort_t f2bf(float f) {
  union { float f; unsigned int u; } x; x.f = f;
  unsigned int r = x.u + 0x7fffu + ((x.u >> 16) & 1u);
  return (ushort_t)(r >> 16);
}

// v_cvt_pk_bf16_f32: D = {lo: bf16(a), hi: bf16(b)} (no builtin on gfx950)
__device__ inline unsigned int cvtpk(float a, float b) {
  unsigned int r;
  asm("v_cvt_pk_bf16_f32 %0, %1, %2" : "=v"(r) : "v"(a), "v"(b));
  return r;
}

// v_permlane32_swap_b32: x[hi lanes] <-> y[lo lanes]
__device__ inline void plswap(unsigned int& x, unsigned int& y) {
  asm("v_permlane32_swap_b32 %0, %1" : "+v"(x), "+v"(y));
}

// ---------------------------------------------------------------------------
// x [M,K] fp32 -> bf16, straight copy. 8 elems/thread.
// ---------------------------------------------------------------------------
__global__ __launch_bounds__(256) void convert_x(const float* __restrict__ in,
                                                 ushort_t* __restrict__ out) {
  int i = (blockIdx.x * 256 + threadIdx.x) * 8;
  float4 a = *(const float4*)(in + i);
  float4 b = *(const float4*)(in + i + 4);
  bf16x8 o;
  o[0] = f2bf(a.x); o[1] = f2bf(a.y); o[2] = f2bf(a.z); o[3] = f2bf(a.w);
  o[4] = f2bf(b.x); o[5] = f2bf(b.y); o[6] = f2bf(b.z); o[7] = f2bf(b.w);
  *(bf16x8*)(out + i) = o;
}

// ---------------------------------------------------------------------------
// W [K,N] fp32 -> W^T [N,K] bf16 via 64x64 LDS tile (stride 65: conflict-free)
// ---------------------------------------------------------------------------
__global__ __launch_bounds__(256) void transpose_w(const float* __restrict__ in,
                                                   ushort_t* __restrict__ out,
                                                   int K, int N) {
  __shared__ float t[64][65];
  const int bn = blockIdx.x * 64, bk = blockIdx.y * 64;
  const int c = threadIdx.x & 63, r0 = threadIdx.x >> 6;
#pragma unroll
  for (int rr = 0; rr < 16; ++rr) {
    int row = rr * 4 + r0;
    t[row][c] = in[(size_t)(bk + row) * N + bn + c];
  }
  __syncthreads();
#pragma unroll
  for (int rr = 0; rr < 16; ++rr) {
    int row = rr * 4 + r0;
    out[(size_t)(bn + row) * K + bk + c] = f2bf(t[c][row]);
  }
}

// ---------------------------------------------------------------------------
// bf16 MFMA GEMM (m97 structure): C[M,N] = A[M,K] @ Bt[N,K]^T + bias.
// 128x128 tile, BK=32, 4 waves x (64x64), global_load_lds width-16 staging,
// XOR-swizzled [m][k-slot] LDS layout.
// SCATTER: N==2304 -> q (pre-scaled QSCALE, [B,H,S,D]) / k ([B,H,S,D]) /
//          v (transposed [B,H,D,S]) bf16 buffers.  else: fp32 [M,N] out.
// ---------------------------------------------------------------------------
template <int N_, int K_, bool SCATTER>
__global__ __launch_bounds__(256) void gemm_mfma(
    const ushort_t* __restrict__ A, const ushort_t* __restrict__ Bt,
    const float* __restrict__ bias, float* __restrict__ outF,
    ushort_t* __restrict__ oq, ushort_t* __restrict__ ok,
    ushort_t* __restrict__ ov) {
  __shared__ __align__(16) ushort_t As[128 * 32];
  __shared__ __align__(16) ushort_t Bs[128 * 32];
  const int tid = threadIdx.x;
  const int w = tid >> 6, lane = tid & 63;
  const int quad = lane >> 4, ln = lane & 15;
  const int bm = blockIdx.y * 128, bn = blockIdx.x * 128;
  const int wm = (w >> 1) * 64, wn = (w & 1) * 64;

  const int sr = lane >> 2;     // row within 16-row chunk
  const int sslot = lane & 3;   // 16B slot within row

  fx4 acc[4][4] = {};

  for (int k0 = 0; k0 < K_; k0 += 32) {
    __syncthreads();
#pragma unroll
    for (int r = 0; r < 2; ++r) {
      const int c = w + r * 4;        // chunk 0..7 (wave-uniform)
      const int m = c * 16 + sr;      // tile row 0..127
      const int kk = k0 + ((sslot ^ (m & 3)) << 3);
      __builtin_amdgcn_global_load_lds(
          (const __attribute__((address_space(1))) unsigned int*)
              (A + (size_t)(bm + m) * K_ + kk),
          (__attribute__((address_space(3))) unsigned int*)(As + c * 512),
          16, 0, 0);
      __builtin_amdgcn_global_load_lds(
          (const __attribute__((address_space(1))) unsigned int*)
              (Bt + (size_t)(bn + m) * K_ + kk),
          (__attribute__((address_space(3))) unsigned int*)(Bs + c * 512),
          16, 0, 0);
    }
    __syncthreads();

    bf16x8 af[4], bfr[4];
#pragma unroll
    for (int i = 0; i < 4; ++i) {
      const int m = wm + i * 16 + ln;
      af[i] = *(const bf16x8*)(As + m * 32 + ((quad ^ (m & 3)) << 3));
    }
#pragma unroll
    for (int j = 0; j < 4; ++j) {
      const int n = wn + j * 16 + ln;
      bfr[j] = *(const bf16x8*)(Bs + n * 32 + ((quad ^ (n & 3)) << 3));
    }
#pragma unroll
    for (int i = 0; i < 4; ++i)
#pragma unroll
      for (int j = 0; j < 4; ++j)
        acc[i][j] = __builtin_amdgcn_mfma_f32_16x16x32_bf16(af[i], bfr[j],
                                                            acc[i][j], 0, 0, 0);
  }

  if (!SCATTER) {
#pragma unroll
    for (int j = 0; j < 4; ++j) {
      const int n = bn + wn + j * 16 + ln;
      const float bv = bias[n];
#pragma unroll
      for (int i = 0; i < 4; ++i) {
        const int m0 = bm + wm + i * 16 + quad * 4;
#pragma unroll
        for (int r = 0; r < 4; ++r)
          outF[(size_t)(m0 + r) * N_ + n] = acc[i][j][r] + bv;
      }
    }
  } else {
    const int t = bn / EMBED;  // 768 % 128 == 0: whole tile in one of q/k/v
#pragma unroll
    for (int j = 0; j < 4; ++j) {
      const int nn = bn + wn + j * 16 + ln;
      const int rem = nn - t * EMBED;
      const int h = rem >> 6, d = rem & 63;
      const float bv = bias[nn];
#pragma unroll
      for (int i = 0; i < 4; ++i) {
        const int m0 = bm + wm + i * 16 + quad * 4;
#pragma unroll
        for (int r = 0; r < 4; ++r) {
          const int m = m0 + r;
          const int b_ = m >> 12, s = m & 4095;
          const float v = acc[i][j][r] + bv;
          if (t == 0)
            oq[((size_t)(b_ * NH + h) * SEQ + s) * HD + d] = f2bf(v * QSCALE);
          else if (t == 1)
            ok[((size_t)(b_ * NH + h) * SEQ + s) * HD + d] = f2bf(v);
          else
            ov[((size_t)(b_ * NH + h) * HD + d) * SEQ + s] = f2bf(v);
        }
      }
    }
  }
}

// ---------------------------------------------------------------------------
// Causal flash attention v4: 32x32x16 MFMA, in-register P, QBLK=64 / 2-wave
// blocks with BACKFILL.
//  * R2 counters: kernel at 2x its DS floor (~42 us incl. conflicts); all
//    pipes <35%; OccupancyPercent 18.4% because grid was exactly 3
//    blocks/CU co-resident with NO backfill -> huge triangle tail.
//  * v4: QBLK=64, 2 waves/block (each wave keeps its 32 q-rows and the
//    identical per-wave 32x32 code), grid (24,64) = 1536 blocks, descending
//    length (qt = 63-y).  LDS still 32 KB (K/V tile q-independent) ->
//    5 blocks/CU resident + queue -> ~10 waves/CU steady, LPT tail ~6%.
//  * Single diagonal k-tile now (QBLK==KBLK): fully-masked krb chunk is
//    skipped outright (w=0 wave skips 8/16 MFMAs on diag tile).
//  * Cost: K/V staged per 64-q block -> 2x DMA volume (810 MB, L2-served).
// ---------------------------------------------------------------------------
__global__ __launch_bounds__(128, 3) void flash_mfma(
    const ushort_t* __restrict__ qb, const ushort_t* __restrict__ kb,
    const ushort_t* __restrict__ vb, ushort_t* __restrict__ attn) {
  __shared__ __align__(16) ushort_t Ks[2][64 * 64];  // 16384 B
  __shared__ __align__(16) ushort_t Vt[2][64 * 64];  // 16384 B

  const int tid = threadIdx.x;
  const int w = tid >> 6;      // wave 0/1 -> q sub-block (32 rows)
  const int lane = tid & 63;
  const int r32 = lane & 31;   // MFMA row index
  const int hf = lane >> 5;    // k-half (lane 0-31 vs 32-63)
  const int gk = r32 & 7;      // granule swizzle key
  const int rc4 = hf * 4;      // rowcode offset

  const int bh = blockIdx.x;   // 0..23 (fast dim, 24%8==0 -> XCD = bh%8)
  const int qt = 63 - (int)blockIdx.y;  // descending length (LPT order)
  const int nkt = qt + 1;

  const size_t base = (size_t)bh * SEQ * HD;
  const ushort_t* Qg = qb + base;
  const ushort_t* Kg = kb + base;
  const ushort_t* Vg = vb + base;  // [HD][SEQ]

  // ---- staging geometry (kt-invariant): 8 chunks, chunk c = w + r2*2 ----
  const int srow = lane >> 3;
  const int sg = (lane & 7) ^ srow;     // logical granule this lane fetches
  const int row0 = w * 8 + srow;        // chunk w row; chunk w+2*r2 = +16*r2
  const ushort_t* kp = Kg + (size_t)row0 * HD + (sg << 3);
  const ushort_t* vp = Vg + (size_t)row0 * SEQ + (sg << 3);

  // ---- Q fragments (kt-invariant): B-operand, lane holds Q[q32][dchunk] ----
  const int qoff = w * 32 + r32;        // q offset within 64-row tile
  const int qglob = qt * 64 + qoff;
  bf16x8 qf[4];
  {
    const ushort_t* qrow = Qg + (size_t)qglob * HD;
#pragma unroll
    for (int dc = 0; dc < 4; ++dc)
      qf[dc] = *(const bf16x8*)(qrow + dc * 16 + hf * 8);
  }

  f32x16 oacc[2] = {};  // O^T: col q = r32 (lane-local), rows d per vblk
  float lsum = 0.f;

  // ---- prologue: stage kt=0 into buf 0; advance pointers to kt=1 ----
#pragma unroll
  for (int r2 = 0; r2 < 4; ++r2) {
    __builtin_amdgcn_global_load_lds(
        (const __attribute__((address_space(1))) unsigned int*)(kp + r2 * (16 * HD)),
        (__attribute__((address_space(3))) unsigned int*)(&Ks[0][(w + r2 * 2) * 512]),
        16, 0, 0);
    __builtin_amdgcn_global_load_lds(
        (const __attribute__((address_space(1))) unsigned int*)(vp + r2 * (16 * SEQ)),
        (__attribute__((address_space(3))) unsigned int*)(&Vt[0][(w + r2 * 2) * 512]),
        16, 0, 0);
  }
  kp += 64 * HD;
  vp += 64;

  for (int kt = 0; kt < nkt; ++kt) {
    const int cur = kt & 1;
    __syncthreads();  // publish buf `cur` (drains in-flight DMA)
    if (kt + 1 < nkt) {  // prefetch kt+1 into the other buffer
      const int nxt = cur ^ 1;
#pragma unroll
      for (int r2 = 0; r2 < 4; ++r2) {
        __builtin_amdgcn_global_load_lds(
            (const __attribute__((address_space(1))) unsigned int*)(kp + r2 * (16 * HD)),
            (__attribute__((address_space(3))) unsigned int*)(&Ks[nxt][(w + r2 * 2) * 512]),
            16, 0, 0);
        __builtin_amdgcn_global_load_lds(
            (const __attribute__((address_space(1))) unsigned int*)(vp + r2 * (16 * SEQ)),
            (__attribute__((address_space(3))) unsigned int*)(&Vt[nxt][(w + r2 * 2) * 512]),
            16, 0, 0);
      }
      kp += 64 * HD;
      vp += 64;
    }

    const bool diag = (kt == nkt - 1);  // single diagonal tile (QBLK==KBLK)

#pragma unroll
    for (int krb = 0; krb < 2; ++krb) {
      if (diag && krb > w) continue;  // fully-masked 32-kr block: p == 0
      // ---- QK^T: S^T[kr 32][q 32], chained over 4 d-chunks ----
      const int krow = (krb * 32 + r32) * 64;
      f32x16 s = {};
#pragma unroll
      for (int dc = 0; dc < 4; ++dc) {
        bf16x8 kf =
            *(const bf16x8*)(&Ks[cur][krow + (((2 * dc + hf) ^ gk) << 3)]);
        s = __builtin_amdgcn_mfma_f32_32x32x16_bf16(kf, qf[dc], s, 0, 0, 0);
      }
      // ---- causal mask: only the diag tile's krb==w chunk straddles ----
      if (diag && krb == w) {
#pragma unroll
        for (int r = 0; r < 16; ++r) {
          const int rowc = (r & 3) + 8 * (r >> 2) + rc4;
          if (rowc > r32) s[r] = -1e30f;
        }
      }
      // ---- exp2 + l ----
      float e[16];
#pragma unroll
      for (int r = 0; r < 16; ++r) {
        e[r] = EXP2F(s[r]);
        lsum += e[r];
      }
      // ---- per 16-kr chunk: pack to bf16, permlane-swap -> pf; PV ----
#pragma unroll
      for (int ch = 0; ch < 2; ++ch) {
        const int rb = ch * 8;
        unsigned int x0 = cvtpk(e[rb + 0], e[rb + 1]);
        unsigned int x1 = cvtpk(e[rb + 2], e[rb + 3]);
        unsigned int y0 = cvtpk(e[rb + 4], e[rb + 5]);
        unsigned int y1 = cvtpk(e[rb + 6], e[rb + 7]);
        plswap(x0, y0);  // x0 -> (j0,j1), y0 -> (j4,j5)
        plswap(x1, y1);  // x1 -> (j2,j3), y1 -> (j6,j7)
        union { unsigned int u[4]; bf16x8 v; } pf;
        pf.u[0] = x0; pf.u[1] = x1; pf.u[2] = y0; pf.u[3] = y1;
        const int c = 2 * krb + ch;       // 16-kr chunk index 0..3
        __builtin_amdgcn_s_setprio(1);
#pragma unroll
        for (int vb2 = 0; vb2 < 2; ++vb2) {
          const int vrow = (vb2 * 32 + r32) * 64;
          bf16x8 vf =
              *(const bf16x8*)(&Vt[cur][vrow + (((2 * c + hf) ^ gk) << 3)]);
          oacc[vb2] =
              __builtin_amdgcn_mfma_f32_32x32x16_bf16(vf, pf.v, oacc[vb2], 0, 0, 0);
        }
        __builtin_amdgcn_s_setprio(0);
      }
    }
  }

  // ---- l reduction (hf pair) + epilogue: O^T/l -> attn bf16 [B,S,E] ----
  lsum += __shfl_xor(lsum, 32);
  const float inv = 1.f / lsum;
  const int b_ = bh / NH, h = bh % NH;
  ushort_t* orow = attn + (size_t)(b_ * SEQ + qglob) * EMBED + h * HD;
#pragma unroll
  for (int vb2 = 0; vb2 < 2; ++vb2)
#pragma unroll
    for (int rq = 0; rq < 4; ++rq) {
      us4 o;
#pragma unroll
      for (int r = 0; r < 4; ++r) o[r] = f2bf(oacc[vb2][rq * 4 + r] * inv);
      *(us4*)(orow + vb2 * 32 + rq * 8 + rc4) = o;
    }
}

extern "C" void kernel_launch(void* const* d_in, const int* in_sizes, int n_in,
                              void* d_out, int out_size, void* d_ws,
                              size_t ws_size, hipStream_t stream) {
  const float* x = (const float*)d_in[0];      // [B,S,E]
  const float* w_qkv = (const float*)d_in[1];  // [E,3E]
  const float* b_qkv = (const float*)d_in[2];  // [3E]
  const float* w_out = (const float*)d_in[3];  // [E,E]
  const float* b_out = (const float*)d_in[4];  // [E]
  float* out = (float*)d_out;                  // [B,S,E] fp32

  const size_t per = (size_t)BATCH * NH * SEQ * HD;  // 6291456
  ushort_t* q_buf = (ushort_t*)d_ws;          // [B,H,S,D] (scaled by QSCALE)
  ushort_t* k_buf = q_buf + per;              // [B,H,S,D]
  ushort_t* v_buf = k_buf + per;              // [B,H,D,S] (transposed)
  ushort_t* attn_buf = v_buf + per;           // [B,S,E] bf16
  ushort_t* xb = attn_buf + per;              // [M,E] bf16
  ushort_t* wqkvT = xb + per;                 // [3E,E] bf16
  ushort_t* woutT = wqkvT + (size_t)N3E * EMBED;  // [E,E] bf16

  convert_x<<<(MROWS * EMBED) / 2048, 256, 0, stream>>>(x, xb);
  transpose_w<<<dim3(N3E / 64, EMBED / 64), 256, 0, stream>>>(w_qkv, wqkvT,
                                                              EMBED, N3E);
  transpose_w<<<dim3(EMBED / 64, EMBED / 64), 256, 0, stream>>>(w_out, woutT,
                                                                EMBED, EMBED);

  dim3 g1(N3E / 128, MROWS / 128);  // (18,64)
  gemm_mfma<N3E, EMBED, true><<<g1, 256, 0, stream>>>(
      xb, wqkvT, b_qkv, nullptr, q_buf, k_buf, v_buf);

  dim3 g2(BATCH * NH, 64);  // bh fast (XCD = bh%8); qt = 63-y (LPT order)
  flash_mfma<<<g2, 128, 0, stream>>>(q_buf, k_buf, v_buf, attn_buf);

  dim3 g3(EMBED / 128, MROWS / 128);  // (6,64)
  gemm_mfma<EMBED, EMBED, false><<<g3, 256, 0, stream>>>(
      attn_buf, woutT, b_out, out, nullptr, nullptr, nullptr);
}

// Round 4
// 255.763 us; speedup vs baseline: 1.1368x; 1.0076x over previous
//
#include <hip/hip_runtime.h>

#define EMBED 768
#define NH 12
#define HD 64
#define SEQ 4096
#define BATCH 2
#define MROWS (BATCH * SEQ)   // 8192
#define N3E (3 * EMBED)       // 2304

typedef short bf16x8 __attribute__((ext_vector_type(8)));  // 8 bf16 = 4 VGPRs
typedef float fx4 __attribute__((ext_vector_type(4)));     // MFMA C/D 16x16
typedef float f32x16 __attribute__((ext_vector_type(16))); // MFMA C/D 32x32
typedef unsigned short ushort_t;
typedef unsigned short us4 __attribute__((ext_vector_type(4)));  // 8B packed

#if __has_builtin(__builtin_amdgcn_exp2f)
#define EXP2F(x) __builtin_amdgcn_exp2f(x)
#else
#define EXP2F(x) exp2f(x)
#endif

// Q pre-scale: (1/sqrt(64)) * log2(e)  -> softmax runs in exp2 domain
#define QSCALE 0.18033688011112042f

// fp32 -> bf16 round-to-nearest-even
__device__ inline ushort_t f2bf(float f) {
  union { float f; unsigned int u; } x; x.f = f;
  unsigned int r = x.u + 0x7fffu + ((x.u >> 16) & 1u);
  return (ushort_t)(r >> 16);
}

// v_cvt_pk_bf16_f32: D = {lo: bf16(a), hi: bf16(b)} (no builtin on gfx950)
__device__ inline unsigned int cvtpk(float a, float b) {
  unsigned int r;
  asm("v_cvt_pk_bf16_f32 %0, %1, %2" : "=v"(r) : "v"(a), "v"(b));
  return r;
}

// v_permlane32_swap_b32: x[hi lanes] <-> y[lo lanes]
__device__ inline void plswap(unsigned int& x, unsigned int& y) {
  asm("v_permlane32_swap_b32 %0, %1" : "+v"(x), "+v"(y));
}

// ---------------------------------------------------------------------------
// x [M,K] fp32 -> bf16, straight copy. 8 elems/thread.
// ---------------------------------------------------------------------------
__global__ __launch_bounds__(256) void convert_x(const float* __restrict__ in,
                                                 ushort_t* __restrict__ out) {
  int i = (blockIdx.x * 256 + threadIdx.x) * 8;
  float4 a = *(const float4*)(in + i);
  float4 b = *(const float4*)(in + i + 4);
  bf16x8 o;
  o[0] = f2bf(a.x); o[1] = f2bf(a.y); o[2] = f2bf(a.z); o[3] = f2bf(a.w);
  o[4] = f2bf(b.x); o[5] = f2bf(b.y); o[6] = f2bf(b.z); o[7] = f2bf(b.w);
  *(bf16x8*)(out + i) = o;
}

// ---------------------------------------------------------------------------
// W [K,N] fp32 -> W^T [N,K] bf16 via 64x64 LDS tile (stride 65: conflict-free)
// ---------------------------------------------------------------------------
__global__ __launch_bounds__(256) void transpose_w(const float* __restrict__ in,
                                                   ushort_t* __restrict__ out,
                                                   int K, int N) {
  __shared__ float t[64][65];
  const int bn = blockIdx.x * 64, bk = blockIdx.y * 64;
  const int c = threadIdx.x & 63, r0 = threadIdx.x >> 6;
#pragma unroll
  for (int rr = 0; rr < 16; ++rr) {
    int row = rr * 4 + r0;
    t[row][c] = in[(size_t)(bk + row) * N + bn + c];
  }
  __syncthreads();
#pragma unroll
  for (int rr = 0; rr < 16; ++rr) {
    int row = rr * 4 + r0;
    out[(size_t)(bn + row) * K + bk + c] = f2bf(t[c][row]);
  }
}

// ---------------------------------------------------------------------------
// bf16 MFMA GEMM (m97 structure): C[M,N] = A[M,K] @ Bt[N,K]^T + bias.
// 128x128 tile, BK=32, 4 waves x (64x64), global_load_lds width-16 staging,
// XOR-swizzled [m][k-slot] LDS layout.
// SCATTER: N==2304 -> q (pre-scaled QSCALE, [B,H,S,D]) / k ([B,H,S,D]) /
//          v (transposed [B,H,D,S]) bf16 buffers.  else: fp32 [M,N] out.
// ---------------------------------------------------------------------------
template <int N_, int K_, bool SCATTER>
__global__ __launch_bounds__(256) void gemm_mfma(
    const ushort_t* __restrict__ A, const ushort_t* __restrict__ Bt,
    const float* __restrict__ bias, float* __restrict__ outF,
    ushort_t* __restrict__ oq, ushort_t* __restrict__ ok,
    ushort_t* __restrict__ ov) {
  __shared__ __align__(16) ushort_t As[128 * 32];
  __shared__ __align__(16) ushort_t Bs[128 * 32];
  const int tid = threadIdx.x;
  const int w = tid >> 6, lane = tid & 63;
  const int quad = lane >> 4, ln = lane & 15;
  const int bm = blockIdx.y * 128, bn = blockIdx.x * 128;
  const int wm = (w >> 1) * 64, wn = (w & 1) * 64;

  const int sr = lane >> 2;     // row within 16-row chunk
  const int sslot = lane & 3;   // 16B slot within row

  fx4 acc[4][4] = {};

  for (int k0 = 0; k0 < K_; k0 += 32) {
    __syncthreads();
#pragma unroll
    for (int r = 0; r < 2; ++r) {
      const int c = w + r * 4;        // chunk 0..7 (wave-uniform)
      const int m = c * 16 + sr;      // tile row 0..127
      const int kk = k0 + ((sslot ^ (m & 3)) << 3);
      __builtin_amdgcn_global_load_lds(
          (const __attribute__((address_space(1))) unsigned int*)
              (A + (size_t)(bm + m) * K_ + kk),
          (__attribute__((address_space(3))) unsigned int*)(As + c * 512),
          16, 0, 0);
      __builtin_amdgcn_global_load_lds(
          (const __attribute__((address_space(1))) unsigned int*)
              (Bt + (size_t)(bn + m) * K_ + kk),
          (__attribute__((address_space(3))) unsigned int*)(Bs + c * 512),
          16, 0, 0);
    }
    __syncthreads();

    bf16x8 af[4], bfr[4];
#pragma unroll
    for (int i = 0; i < 4; ++i) {
      const int m = wm + i * 16 + ln;
      af[i] = *(const bf16x8*)(As + m * 32 + ((quad ^ (m & 3)) << 3));
    }
#pragma unroll
    for (int j = 0; j < 4; ++j) {
      const int n = wn + j * 16 + ln;
      bfr[j] = *(const bf16x8*)(Bs + n * 32 + ((quad ^ (n & 3)) << 3));
    }
#pragma unroll
    for (int i = 0; i < 4; ++i)
#pragma unroll
      for (int j = 0; j < 4; ++j)
        acc[i][j] = __builtin_amdgcn_mfma_f32_16x16x32_bf16(af[i], bfr[j],
                                                            acc[i][j], 0, 0, 0);
  }

  if (!SCATTER) {
#pragma unroll
    for (int j = 0; j < 4; ++j) {
      const int n = bn + wn + j * 16 + ln;
      const float bv = bias[n];
#pragma unroll
      for (int i = 0; i < 4; ++i) {
        const int m0 = bm + wm + i * 16 + quad * 4;
#pragma unroll
        for (int r = 0; r < 4; ++r)
          outF[(size_t)(m0 + r) * N_ + n] = acc[i][j][r] + bv;
      }
    }
  } else {
    const int t = bn / EMBED;  // 768 % 128 == 0: whole tile in one of q/k/v
#pragma unroll
    for (int j = 0; j < 4; ++j) {
      const int nn = bn + wn + j * 16 + ln;
      const int rem = nn - t * EMBED;
      const int h = rem >> 6, d = rem & 63;
      const float bv = bias[nn];
#pragma unroll
      for (int i = 0; i < 4; ++i) {
        const int m0 = bm + wm + i * 16 + quad * 4;
#pragma unroll
        for (int r = 0; r < 4; ++r) {
          const int m = m0 + r;
          const int b_ = m >> 12, s = m & 4095;
          const float v = acc[i][j][r] + bv;
          if (t == 0)
            oq[((size_t)(b_ * NH + h) * SEQ + s) * HD + d] = f2bf(v * QSCALE);
          else if (t == 1)
            ok[((size_t)(b_ * NH + h) * SEQ + s) * HD + d] = f2bf(v);
          else
            ov[((size_t)(b_ * NH + h) * HD + d) * SEQ + s] = f2bf(v);
        }
      }
    }
  }
}

// ---------------------------------------------------------------------------
// Causal flash attention v5: 32x32x16 MFMA, in-register P, QBLK=64 / 2-wave
// blocks -- ILP-RESTRUCTURED iteration (latency-chain fix).
//  * R3 evidence: flash pinned at ~90 us across 3 occupancy configs; no pipe
//    >37%; back-computed per-iteration latency ~3300 cyc at ~1.5 waves/SIMD
//    -> LATENCY-BOUND on the serial source chain
//    (QK0 -> sm0 -> PV0 -> QK1 -> sm1 -> PV1 + 32-deep lsum chain).
//  * v5 single-basic-block iteration:
//      - both QK krb chains issued interleaved (2 independent 4-deep chains)
//      - diag handled by masking only (no branch; w=0 wastes 8 MFMAs on the
//        one diag tile per block -- negligible)
//      - all 32 exp2 together; lsum via pairwise tree (depth 5, not 32)
//      - pack+PV per chunk; PV = 2 interleaved 4-deep chains; setprio(1)
//    Predicted chain ~1000 cyc (was ~3300).
//  * Everything else identical to v4 (grid (24,64) LPT, 32 KB LDS, DMA dbuf).
// ---------------------------------------------------------------------------
__global__ __launch_bounds__(128, 3) void flash_mfma(
    const ushort_t* __restrict__ qb, const ushort_t* __restrict__ kb,
    const ushort_t* __restrict__ vb, ushort_t* __restrict__ attn) {
  __shared__ __align__(16) ushort_t Ks[2][64 * 64];  // 16384 B
  __shared__ __align__(16) ushort_t Vt[2][64 * 64];  // 16384 B

  const int tid = threadIdx.x;
  const int w = tid >> 6;      // wave 0/1 -> q sub-block (32 rows)
  const int lane = tid & 63;
  const int r32 = lane & 31;   // MFMA row index
  const int hf = lane >> 5;    // k-half (lane 0-31 vs 32-63)
  const int gk = r32 & 7;      // granule swizzle key
  const int rc4 = hf * 4;      // rowcode offset

  const int bh = blockIdx.x;   // 0..23 (fast dim, 24%8==0 -> XCD = bh%8)
  const int qt = 63 - (int)blockIdx.y;  // descending length (LPT order)
  const int nkt = qt + 1;

  const size_t base = (size_t)bh * SEQ * HD;
  const ushort_t* Qg = qb + base;
  const ushort_t* Kg = kb + base;
  const ushort_t* Vg = vb + base;  // [HD][SEQ]

  // ---- staging geometry (kt-invariant): 8 chunks, chunk c = w + r2*2 ----
  const int srow = lane >> 3;
  const int sg = (lane & 7) ^ srow;     // logical granule this lane fetches
  const int row0 = w * 8 + srow;        // chunk w row; chunk w+2*r2 = +16*r2
  const ushort_t* kp = Kg + (size_t)row0 * HD + (sg << 3);
  const ushort_t* vp = Vg + (size_t)row0 * SEQ + (sg << 3);

  // ---- Q fragments (kt-invariant): B-operand, lane holds Q[q32][dchunk] ----
  const int qoff = w * 32 + r32;        // q offset within 64-row tile
  const int qglob = qt * 64 + qoff;
  bf16x8 qf[4];
  {
    const ushort_t* qrow = Qg + (size_t)qglob * HD;
#pragma unroll
    for (int dc = 0; dc < 4; ++dc)
      qf[dc] = *(const bf16x8*)(qrow + dc * 16 + hf * 8);
  }

  f32x16 oacc[2] = {};  // O^T: col q = r32 (lane-local), rows d per vblk
  float lsum = 0.f;

  // ---- prologue: stage kt=0 into buf 0; advance pointers to kt=1 ----
#pragma unroll
  for (int r2 = 0; r2 < 4; ++r2) {
    __builtin_amdgcn_global_load_lds(
        (const __attribute__((address_space(1))) unsigned int*)(kp + r2 * (16 * HD)),
        (__attribute__((address_space(3))) unsigned int*)(&Ks[0][(w + r2 * 2) * 512]),
        16, 0, 0);
    __builtin_amdgcn_global_load_lds(
        (const __attribute__((address_space(1))) unsigned int*)(vp + r2 * (16 * SEQ)),
        (__attribute__((address_space(3))) unsigned int*)(&Vt[0][(w + r2 * 2) * 512]),
        16, 0, 0);
  }
  kp += 64 * HD;
  vp += 64;

  for (int kt = 0; kt < nkt; ++kt) {
    const int cur = kt & 1;
    __syncthreads();  // publish buf `cur` (drains in-flight DMA)
    if (kt + 1 < nkt) {  // prefetch kt+1 into the other buffer
      const int nxt = cur ^ 1;
#pragma unroll
      for (int r2 = 0; r2 < 4; ++r2) {
        __builtin_amdgcn_global_load_lds(
            (const __attribute__((address_space(1))) unsigned int*)(kp + r2 * (16 * HD)),
            (__attribute__((address_space(3))) unsigned int*)(&Ks[nxt][(w + r2 * 2) * 512]),
            16, 0, 0);
        __builtin_amdgcn_global_load_lds(
            (const __attribute__((address_space(1))) unsigned int*)(vp + r2 * (16 * SEQ)),
            (__attribute__((address_space(3))) unsigned int*)(&Vt[nxt][(w + r2 * 2) * 512]),
            16, 0, 0);
      }
      kp += 64 * HD;
      vp += 64;
    }

    const bool diag = (kt == nkt - 1);  // single diagonal tile (QBLK==KBLK)

    // ---- QK^T both 32-kr halves, independent interleaved MFMA chains ----
    f32x16 s0 = {}, s1 = {};
#pragma unroll
    for (int dc = 0; dc < 4; ++dc) {
      const int slot = ((2 * dc + hf) ^ gk) << 3;
      bf16x8 kf0 = *(const bf16x8*)(&Ks[cur][r32 * 64 + slot]);
      bf16x8 kf1 = *(const bf16x8*)(&Ks[cur][(32 + r32) * 64 + slot]);
      s0 = __builtin_amdgcn_mfma_f32_32x32x16_bf16(kf0, qf[dc], s0, 0, 0, 0);
      s1 = __builtin_amdgcn_mfma_f32_32x32x16_bf16(kf1, qf[dc], s1, 0, 0, 0);
    }

    // ---- causal mask (diag tile only; wave-uniform branch, no skip) ----
    if (diag) {
      if (w == 0) {
#pragma unroll
        for (int r = 0; r < 16; ++r) {
          const int rowc = (r & 3) + 8 * (r >> 2) + rc4;
          if (rowc > r32) s0[r] = -1e30f;
          s1[r] = -1e30f;  // kr 32..63 all > q row (q < 32)
        }
      } else {
#pragma unroll
        for (int r = 0; r < 16; ++r) {
          const int rowc = (r & 3) + 8 * (r >> 2) + rc4;
          if (rowc > r32) s1[r] = -1e30f;
        }
      }
    }

    // ---- exp2 all 32 ----
    float e0[16], e1[16];
#pragma unroll
    for (int r = 0; r < 16; ++r) {
      e0[r] = EXP2F(s0[r]);
      e1[r] = EXP2F(s1[r]);
    }
    // ---- l: pairwise tree (depth 4) + single chain add ----
    {
      float ta = ((e0[0] + e0[1]) + (e0[2] + e0[3])) +
                 ((e0[4] + e0[5]) + (e0[6] + e0[7]));
      float tb = ((e0[8] + e0[9]) + (e0[10] + e0[11])) +
                 ((e0[12] + e0[13]) + (e0[14] + e0[15]));
      float tc = ((e1[0] + e1[1]) + (e1[2] + e1[3])) +
                 ((e1[4] + e1[5]) + (e1[6] + e1[7]));
      float td = ((e1[8] + e1[9]) + (e1[10] + e1[11])) +
                 ((e1[12] + e1[13]) + (e1[14] + e1[15]));
      lsum += (ta + tb) + (tc + td);
    }

    // ---- pack to bf16 (cvt_pk + permlane32_swap) and PV per 16-kr chunk ----
    __builtin_amdgcn_s_setprio(1);
#define PVCHUNK(c, E, rb)                                                     \
    {                                                                         \
      unsigned int x0 = cvtpk(E[(rb) + 0], E[(rb) + 1]);                      \
      unsigned int x1 = cvtpk(E[(rb) + 2], E[(rb) + 3]);                      \
      unsigned int y0 = cvtpk(E[(rb) + 4], E[(rb) + 5]);                      \
      unsigned int y1 = cvtpk(E[(rb) + 6], E[(rb) + 7]);                      \
      plswap(x0, y0);                                                         \
      plswap(x1, y1);                                                         \
      union { unsigned int u[4]; bf16x8 v; } pf;                              \
      pf.u[0] = x0; pf.u[1] = x1; pf.u[2] = y0; pf.u[3] = y1;                 \
      const int slot = ((2 * (c) + hf) ^ gk) << 3;                            \
      bf16x8 vfa = *(const bf16x8*)(&Vt[cur][r32 * 64 + slot]);               \
      bf16x8 vfb = *(const bf16x8*)(&Vt[cur][(32 + r32) * 64 + slot]);        \
      oacc[0] = __builtin_amdgcn_mfma_f32_32x32x16_bf16(vfa, pf.v, oacc[0],   \
                                                        0, 0, 0);             \
      oacc[1] = __builtin_amdgcn_mfma_f32_32x32x16_bf16(vfb, pf.v, oacc[1],   \
                                                        0, 0, 0);             \
    }
    PVCHUNK(0, e0, 0)
    PVCHUNK(1, e0, 8)
    PVCHUNK(2, e1, 0)
    PVCHUNK(3, e1, 8)
#undef PVCHUNK
    __builtin_amdgcn_s_setprio(0);
  }

  // ---- l reduction (hf pair) + epilogue: O^T/l -> attn bf16 [B,S,E] ----
  lsum += __shfl_xor(lsum, 32);
  const float inv = 1.f / lsum;
  const int b_ = bh / NH, h = bh % NH;
  ushort_t* orow = attn + (size_t)(b_ * SEQ + qglob) * EMBED + h * HD;
#pragma unroll
  for (int vb2 = 0; vb2 < 2; ++vb2)
#pragma unroll
    for (int rq = 0; rq < 4; ++rq) {
      us4 o;
#pragma unroll
      for (int r = 0; r < 4; ++r) o[r] = f2bf(oacc[vb2][rq * 4 + r] * inv);
      *(us4*)(orow + vb2 * 32 + rq * 8 + rc4) = o;
    }
}

extern "C" void kernel_launch(void* const* d_in, const int* in_sizes, int n_in,
                              void* d_out, int out_size, void* d_ws,
                              size_t ws_size, hipStream_t stream) {
  const float* x = (const float*)d_in[0];      // [B,S,E]
  const float* w_qkv = (const float*)d_in[1];  // [E,3E]
  const float* b_qkv = (const float*)d_in[2];  // [3E]
  const float* w_out = (const float*)d_in[3];  // [E,E]
  const float* b_out = (const float*)d_in[4];  // [E]
  float* out = (float*)d_out;                  // [B,S,E] fp32

  const size_t per = (size_t)BATCH * NH * SEQ * HD;  // 6291456
  ushort_t* q_buf = (ushort_t*)d_ws;          // [B,H,S,D] (scaled by QSCALE)
  ushort_t* k_buf = q_buf + per;              // [B,H,S,D]
  ushort_t* v_buf = k_buf + per;              // [B,H,D,S] (transposed)
  ushort_t* attn_buf = v_buf + per;           // [B,S,E] bf16
  ushort_t* xb = attn_buf + per;              // [M,E] bf16
  ushort_t* wqkvT = xb + per;                 // [3E,E] bf16
  ushort_t* woutT = wqkvT + (size_t)N3E * EMBED;  // [E,E] bf16

  convert_x<<<(MROWS * EMBED) / 2048, 256, 0, stream>>>(x, xb);
  transpose_w<<<dim3(N3E / 64, EMBED / 64), 256, 0, stream>>>(w_qkv, wqkvT,
                                                              EMBED, N3E);
  transpose_w<<<dim3(EMBED / 64, EMBED / 64), 256, 0, stream>>>(w_out, woutT,
                                                                EMBED, EMBED);

  dim3 g1(N3E / 128, MROWS / 128);  // (18,64)
  gemm_mfma<N3E, EMBED, true><<<g1, 256, 0, stream>>>(
      xb, wqkvT, b_qkv, nullptr, q_buf, k_buf, v_buf);

  dim3 g2(BATCH * NH, 64);  // bh fast (XCD = bh%8); qt = 63-y (LPT order)
  flash_mfma<<<g2, 128, 0, stream>>>(q_buf, k_buf, v_buf, attn_buf);

  dim3 g3(EMBED / 128, MROWS / 128);  // (6,64)
  gemm_mfma<EMBED, EMBED, false><<<g3, 256, 0, stream>>>(
      attn_buf, woutT, b_out, out, nullptr, nullptr, nullptr);
}